// Round 1
// baseline (776.797 us; speedup 1.0000x reference)
//
#include <hip/hip_runtime.h>

#define D 128
#define NEDGES 500000
#define NNODES 100000

typedef short short8 __attribute__((ext_vector_type(8)));
typedef float f32x4 __attribute__((ext_vector_type(4)));
typedef unsigned short us4 __attribute__((ext_vector_type(4)));
typedef unsigned short us8 __attribute__((ext_vector_type(8)));

static __device__ __forceinline__ unsigned short f2bf(float f) {
  unsigned u = __builtin_bit_cast(unsigned, f);
  u += 0x7fff + ((u >> 16) & 1);   // RNE
  return (unsigned short)(u >> 16);
}

static __device__ __forceinline__ unsigned short f2h(float f) {
  return __builtin_bit_cast(unsigned short, (_Float16)f);
}

static __device__ __forceinline__ float h2f(unsigned short u) {
  return (float)__builtin_bit_cast(_Float16, u);
}

static __device__ __forceinline__ short8 cvt8v(f32x4 a, f32x4 b) {
  short8 r;
  r[0] = (short)f2bf(a[0]); r[1] = (short)f2bf(a[1]);
  r[2] = (short)f2bf(a[2]); r[3] = (short)f2bf(a[3]);
  r[4] = (short)f2bf(b[0]); r[5] = (short)f2bf(b[1]);
  r[6] = (short)f2bf(b[2]); r[7] = (short)f2bf(b[3]);
  return r;
}

// ---------------- new path: split-projection ----------------
// W1 = [W1s; W1r; W1e] (384x128). Precompute Ps = node@W1s, Pr = node@W1r
// once per launch (fp16), so the edge kernel's gather is a cheap additive
// load instead of an MFMA operand.

// Weight transpose to bf16, A-fragment layout [row][k] (row = hidden/out unit).
__global__ void prep_weights2(const float* __restrict__ W1,
                              const float* __restrict__ W2,
                              unsigned short* __restrict__ WnS,
                              unsigned short* __restrict__ WnR,
                              unsigned short* __restrict__ WnE,
                              unsigned short* __restrict__ Wt2) {
  int tid = blockIdx.x * 256 + threadIdx.x;   // 65536 total
  int seg = tid >> 14;
  int t = tid & 16383;
  int row = t >> 7;    // hidden/out unit
  int k = t & 127;
  if (seg == 0)      WnS[t] = f2bf(W1[k * 128 + row]);
  else if (seg == 1) WnR[t] = f2bf(W1[(128 + k) * 128 + row]);
  else if (seg == 2) WnE[t] = f2bf(W1[(256 + k) * 128 + row]);
  else               Wt2[t] = f2bf(W2[k * 128 + row]);
}

// Ps/Pr row layout (128 fp16 elems per node): offset = quad*32 + m*4 + r
// holds feature h = m*16 + quad*4 + r  -> matches MFMA C-fragment exactly,
// so the edge kernel's lane (col,quad) loads its 64 contiguous bytes.
__global__ __launch_bounds__(256, 4) void node_proj(
    const float* __restrict__ node,
    const unsigned short* __restrict__ WnS,
    const unsigned short* __restrict__ WnR,
    unsigned short* __restrict__ Ps,
    unsigned short* __restrict__ Pr) {
  const int lane = threadIdx.x & 63;
  const int wave = threadIdx.x >> 6;
  const int col = lane & 15;
  const int quad = lane >> 4;
  const int nBase = blockIdx.x * 64 + wave * 16;
  if (nBase >= NNODES) return;   // NNODES % 16 == 0 -> wave-exact

  const float* src = node + (size_t)(nBase + col) * D + quad * 8;
  f32x4 c[4][2];
#pragma unroll
  for (int kk = 0; kk < 4; ++kk) {
    c[kk][0] = *(const f32x4*)(src + kk * 32);
    c[kk][1] = *(const f32x4*)(src + kk * 32 + 4);
  }
  f32x4 accS[8], accR[8];
  const f32x4 zero = {0.f, 0.f, 0.f, 0.f};
#pragma unroll
  for (int m = 0; m < 8; ++m) { accS[m] = zero; accR[m] = zero; }

#pragma unroll
  for (int kk = 0; kk < 4; ++kk) {
    short8 bf = cvt8v(c[kk][0], c[kk][1]);
    const int ko = kk * 32 + quad * 8;
#pragma unroll
    for (int m = 0; m < 8; ++m) {
      short8 as = *(const short8*)(WnS + (size_t)(m * 16 + col) * 128 + ko);
      accS[m] = __builtin_amdgcn_mfma_f32_16x16x32_bf16(as, bf, accS[m], 0, 0, 0);
      short8 ar = *(const short8*)(WnR + (size_t)(m * 16 + col) * 128 + ko);
      accR[m] = __builtin_amdgcn_mfma_f32_16x16x32_bf16(ar, bf, accR[m], 0, 0, 0);
    }
  }

  unsigned short* ps = Ps + (size_t)(nBase + col) * D + quad * 32;
  unsigned short* pr = Pr + (size_t)(nBase + col) * D + quad * 32;
#pragma unroll
  for (int m = 0; m < 8; m += 2) {
    us8 w1v, w2v;
#pragma unroll
    for (int r = 0; r < 4; ++r) {
      w1v[r] = f2h(accS[m][r]);     w1v[4 + r] = f2h(accS[m + 1][r]);
      w2v[r] = f2h(accR[m][r]);     w2v[4 + r] = f2h(accR[m + 1][r]);
    }
    *(us8*)(ps + m * 4) = w1v;
    *(us8*)(pr + m * 4) = w2v;
  }
}

// One wave = 16 edges. Stream edge_attr through K=128 GEMM (nontemporal),
// gather Ps/Pr rows as fp16 adds issued up-front, ReLU, GEMM2, LayerNorm.
__global__ __launch_bounds__(256, 4) void edge_mlp(
    const float* __restrict__ edge,
    const int* __restrict__ send, const int* __restrict__ recv,
    const unsigned short* __restrict__ WnE,
    const unsigned short* __restrict__ Wt2,
    const unsigned short* __restrict__ Ps,
    const unsigned short* __restrict__ Pr,
    const float* __restrict__ b1, const float* __restrict__ b2,
    const float* __restrict__ gamma, const float* __restrict__ beta,
    float* __restrict__ out) {
  __shared__ unsigned short hbuf[4][16][136];

  const int lane = threadIdx.x & 63;
  const int wave = threadIdx.x >> 6;
  const int col = lane & 15;
  const int quad = lane >> 4;
  const int q4 = quad * 4;
  const int eBase = blockIdx.x * 64 + wave * 16;
  const bool active = eBase < NEDGES;   // NEDGES % 16 == 0 -> wave-exact

  if (active) {
    const int e = eBase + col;
    const float* ge = edge + (size_t)e * D + quad * 8;

    // stream edge row: 4 chunks x 32B per lane, all issued up front
    f32x4 c[4][2];
#pragma unroll
    for (int kk = 0; kk < 4; ++kk) {
      c[kk][0] = __builtin_nontemporal_load((const f32x4*)(ge + kk * 32));
      c[kk][1] = __builtin_nontemporal_load((const f32x4*)(ge + kk * 32 + 4));
    }

    // gathers: 2 x 64B fp16 per lane, issued before the MFMA loop
    const int si = send[e];
    const int ri = recv[e];
    const us8* ps = (const us8*)(Ps + (size_t)si * D + quad * 32);
    const us8* pr = (const us8*)(Pr + (size_t)ri * D + quad * 32);
    us8 gs[4], gr[4];
#pragma unroll
    for (int i = 0; i < 4; ++i) { gs[i] = ps[i]; gr[i] = pr[i]; }

    f32x4 acc[8];
#pragma unroll
    for (int m = 0; m < 8; ++m)
      acc[m] = *(const f32x4*)(b1 + m * 16 + q4);

    // edge-segment projection: h_e = edge @ W1e
#pragma unroll
    for (int kk = 0; kk < 4; ++kk) {
      short8 bf = cvt8v(c[kk][0], c[kk][1]);
      const int ko = kk * 32 + quad * 8;
#pragma unroll
      for (int m = 0; m < 8; ++m) {
        short8 af = *(const short8*)(WnE + (size_t)(m * 16 + col) * 128 + ko);
        acc[m] = __builtin_amdgcn_mfma_f32_16x16x32_bf16(af, bf, acc[m], 0, 0, 0);
      }
    }

    // + Ps[send] + Pr[recv], ReLU, pack bf16 to LDS
#pragma unroll
    for (int m = 0; m < 8; ++m) {
      const int i = m >> 1, b = (m & 1) * 4;
      f32x4 v = acc[m];
#pragma unroll
      for (int r = 0; r < 4; ++r)
        v[r] += h2f(gs[i][b + r]) + h2f(gr[i][b + r]);
      us4 w;
      w[0] = f2bf(fmaxf(v[0], 0.f));
      w[1] = f2bf(fmaxf(v[1], 0.f));
      w[2] = f2bf(fmaxf(v[2], 0.f));
      w[3] = f2bf(fmaxf(v[3], 0.f));
      *(us4*)&hbuf[wave][col][m * 16 + q4] = w;
    }
  }

  __syncthreads();

  if (active) {
    f32x4 acc2[8];
#pragma unroll
    for (int m = 0; m < 8; ++m)
      acc2[m] = *(const f32x4*)(b2 + m * 16 + q4);
#pragma unroll
    for (int kk = 0; kk < 4; ++kk) {
      const int kb = kk * 32 + quad * 8;
      short8 bf = *(const short8*)&hbuf[wave][col][kb];
#pragma unroll
      for (int m = 0; m < 8; ++m) {
        short8 af = *(const short8*)(Wt2 + (size_t)(m * 16 + col) * 128 + kb);
        acc2[m] = __builtin_amdgcn_mfma_f32_16x16x32_bf16(af, bf, acc2[m], 0, 0, 0);
      }
    }
    float s = 0.f, ss = 0.f;
#pragma unroll
    for (int m = 0; m < 8; ++m)
#pragma unroll
      for (int r = 0; r < 4; ++r) {
        float v = acc2[m][r];
        s += v; ss += v * v;
      }
    s += __shfl_xor(s, 16);  s += __shfl_xor(s, 32);
    ss += __shfl_xor(ss, 16); ss += __shfl_xor(ss, 32);
    const float mean = s * (1.f / 128.f);
    const float var = ss * (1.f / 128.f) - mean * mean;
    const float rstd = rsqrtf(var + 1e-5f);
    float* op = out + (size_t)(eBase + col) * D;
#pragma unroll
    for (int m = 0; m < 8; ++m) {
      f32x4 gv = *(const f32x4*)(gamma + m * 16 + q4);
      f32x4 bv = *(const f32x4*)(beta + m * 16 + q4);
      f32x4 o;
#pragma unroll
      for (int r = 0; r < 4; ++r)
        o[r] = (acc2[m][r] - mean) * rstd * gv[r] + bv[r];
      __builtin_nontemporal_store(o, (f32x4*)(op + m * 16 + q4));
    }
  }
}

// ---------------- fallback path (previous kernel, used if ws too small) ----

__global__ void prep_weights(const float* __restrict__ W1,
                             const float* __restrict__ W2,
                             unsigned short* __restrict__ Wt1,
                             unsigned short* __restrict__ Wt2) {
  int tid = blockIdx.x * 256 + threadIdx.x;
  if (tid < 128 * 384) {
    int h = tid / 384, k = tid % 384;
    Wt1[tid] = f2bf(W1[k * 128 + h]);
  } else {
    int t2 = tid - 128 * 384;
    if (t2 < 128 * 128) {
      int o = t2 / 128, h = t2 % 128;
      Wt2[t2] = f2bf(W2[h * 128 + o]);
    }
  }
}

__global__ __launch_bounds__(256, 4) void edge_kernel(
    const float* __restrict__ node, const float* __restrict__ edge,
    const int* __restrict__ send, const int* __restrict__ recv,
    const unsigned short* __restrict__ Wt1,
    const unsigned short* __restrict__ Wt2,
    const float* __restrict__ b1, const float* __restrict__ b2,
    const float* __restrict__ gamma, const float* __restrict__ beta,
    float* __restrict__ out) {
  __shared__ unsigned short hbuf[4][32][136];

  const int lane = threadIdx.x & 63;
  const int wave = threadIdx.x >> 6;
  const int col = lane & 15;
  const int quad = lane >> 4;
  const int q4 = quad * 4;
  const int eBase = blockIdx.x * 128 + wave * 32;
  const bool active = eBase < NEDGES;

  if (active) {
    const int e0 = eBase + col;
    const int e1 = eBase + 16 + col;
    const float* g0s = node + (size_t)send[e0] * D;
    const float* g0r = node + (size_t)recv[e0] * D;
    const float* g0e = edge + (size_t)e0 * D;
    const float* g1s = node + (size_t)send[e1] * D;
    const float* g1r = node + (size_t)recv[e1] * D;
    const float* g1e = edge + (size_t)e1 * D;

    f32x4 acc[2][8];
#pragma unroll
    for (int m = 0; m < 8; ++m) {
      f32x4 bv = *(const f32x4*)(b1 + m * 16 + q4);
      acc[0][m] = bv; acc[1][m] = bv;
    }

    f32x4 pl[2][2][2];
#define SRC0(seg) ((seg) == 0 ? g0s : (seg) == 1 ? g0r : g0e)
#define SRC1(seg) ((seg) == 0 ? g1s : (seg) == 1 ? g1r : g1e)
#define ISSUE(kk, slot)                                         \
    {                                                           \
      const int seg_ = (kk) >> 2;                               \
      const int ks_ = ((kk) & 3) * 32 + quad * 8;               \
      pl[slot][0][0] = *(const f32x4*)(SRC0(seg_) + ks_);       \
      pl[slot][0][1] = *(const f32x4*)(SRC0(seg_) + ks_ + 4);   \
      pl[slot][1][0] = *(const f32x4*)(SRC1(seg_) + ks_);       \
      pl[slot][1][1] = *(const f32x4*)(SRC1(seg_) + ks_ + 4);   \
    }

    ISSUE(0, 0)
    ISSUE(1, 1)
#pragma unroll
    for (int kk = 0; kk < 12; ++kk) {
      const int slot = kk & 1;
      short8 bf0 = cvt8v(pl[slot][0][0], pl[slot][0][1]);
      short8 bf1 = cvt8v(pl[slot][1][0], pl[slot][1][1]);
      if (kk + 2 < 12) ISSUE(kk + 2, slot)
      const int kfull = kk * 32 + quad * 8;
#pragma unroll
      for (int m = 0; m < 8; ++m) {
        short8 af = *(const short8*)(Wt1 + (size_t)(m * 16 + col) * 384 + kfull);
        acc[0][m] = __builtin_amdgcn_mfma_f32_16x16x32_bf16(af, bf0, acc[0][m], 0, 0, 0);
        acc[1][m] = __builtin_amdgcn_mfma_f32_16x16x32_bf16(af, bf1, acc[1][m], 0, 0, 0);
      }
    }
#undef ISSUE
#undef SRC0
#undef SRC1

#pragma unroll
    for (int g = 0; g < 2; ++g) {
#pragma unroll
      for (int m = 0; m < 8; ++m) {
        f32x4 v = acc[g][m];
        us4 w;
        w.x = f2bf(v[0] > 0.f ? v[0] : 0.f);
        w.y = f2bf(v[1] > 0.f ? v[1] : 0.f);
        w.z = f2bf(v[2] > 0.f ? v[2] : 0.f);
        w.w = f2bf(v[3] > 0.f ? v[3] : 0.f);
        *(us4*)&hbuf[wave][g * 16 + col][m * 16 + q4] = w;
      }
    }
  }

  __syncthreads();

  if (active) {
    f32x4 acc2[2][8];
#pragma unroll
    for (int m = 0; m < 8; ++m) {
      f32x4 bv = *(const f32x4*)(b2 + m * 16 + q4);
      acc2[0][m] = bv; acc2[1][m] = bv;
    }
#pragma unroll
    for (int kk = 0; kk < 4; ++kk) {
      const int kb = kk * 32 + quad * 8;
      short8 bf0 = *(const short8*)&hbuf[wave][col][kb];
      short8 bf1 = *(const short8*)&hbuf[wave][16 + col][kb];
#pragma unroll
      for (int m = 0; m < 8; ++m) {
        short8 af = *(const short8*)(Wt2 + (size_t)(m * 16 + col) * 128 + kb);
        acc2[0][m] = __builtin_amdgcn_mfma_f32_16x16x32_bf16(af, bf0, acc2[0][m], 0, 0, 0);
        acc2[1][m] = __builtin_amdgcn_mfma_f32_16x16x32_bf16(af, bf1, acc2[1][m], 0, 0, 0);
      }
    }
#pragma unroll
    for (int g = 0; g < 2; ++g) {
      float s = 0.f, ss = 0.f;
#pragma unroll
      for (int m = 0; m < 8; ++m) {
#pragma unroll
        for (int r = 0; r < 4; ++r) {
          float v = acc2[g][m][r];
          s += v; ss += v * v;
        }
      }
      s += __shfl_xor(s, 16);  s += __shfl_xor(s, 32);
      ss += __shfl_xor(ss, 16); ss += __shfl_xor(ss, 32);
      const float mean = s * (1.f / 128.f);
      const float var = ss * (1.f / 128.f) - mean * mean;
      const float rstd = rsqrtf(var + 1e-5f);
      const int e = eBase + g * 16 + col;
      float* op = out + (size_t)e * D;
#pragma unroll
      for (int m = 0; m < 8; ++m) {
        f32x4 gv = *(const f32x4*)(gamma + m * 16 + q4);
        f32x4 bv = *(const f32x4*)(beta + m * 16 + q4);
        f32x4 o;
#pragma unroll
        for (int r = 0; r < 4; ++r)
          o[r] = (acc2[g][m][r] - mean) * rstd * gv[r] + bv[r];
        *(f32x4*)(op + m * 16 + q4) = o;
      }
    }
  }
}

extern "C" void kernel_launch(void* const* d_in, const int* in_sizes, int n_in,
                              void* d_out, int out_size, void* d_ws, size_t ws_size,
                              hipStream_t stream) {
  const float* node  = (const float*)d_in[0];
  const float* edge  = (const float*)d_in[1];
  const int*   send  = (const int*)d_in[2];
  const int*   recv  = (const int*)d_in[3];
  const float* W1    = (const float*)d_in[4];
  const float* b1    = (const float*)d_in[5];
  const float* W2    = (const float*)d_in[6];
  const float* b2    = (const float*)d_in[7];
  const float* gam   = (const float*)d_in[8];
  const float* bet   = (const float*)d_in[9];
  float* out = (float*)d_out;

  const size_t wbytes = (size_t)4 * 128 * 128 * sizeof(unsigned short);  // 128 KiB
  const size_t pbytes = (size_t)2 * NNODES * D * sizeof(unsigned short); // 51.2 MB

  if (ws_size >= wbytes + pbytes) {
    unsigned short* WnS = (unsigned short*)d_ws;
    unsigned short* WnR = WnS + 128 * 128;
    unsigned short* WnE = WnR + 128 * 128;
    unsigned short* Wt2 = WnE + 128 * 128;
    unsigned short* Ps  = Wt2 + 128 * 128;
    unsigned short* Pr  = Ps + (size_t)NNODES * D;

    prep_weights2<<<256, 256, 0, stream>>>(W1, W2, WnS, WnR, WnE, Wt2);
    node_proj<<<(NNODES + 63) / 64, 256, 0, stream>>>(node, WnS, WnR, Ps, Pr);
    edge_mlp<<<(NEDGES + 63) / 64, 256, 0, stream>>>(edge, send, recv, WnE, Wt2,
                                                     Ps, Pr, b1, b2, gam, bet, out);
  } else {
    unsigned short* Wt1 = (unsigned short*)d_ws;
    unsigned short* Wt2 = Wt1 + 128 * 384;
    prep_weights<<<256, 256, 0, stream>>>(W1, W2, Wt1, Wt2);
    const int nblocks = (NEDGES + 127) / 128;
    edge_kernel<<<nblocks, 256, 0, stream>>>(node, edge, send, recv, Wt1, Wt2,
                                             b1, b2, gam, bet, out);
  }
}

// Round 3
// 538.541 us; speedup vs baseline: 1.4424x; 1.4424x over previous
//
#include <hip/hip_runtime.h>

#define D 128
#define NEDGES 500000
#define NNODES 100000

typedef short short8 __attribute__((ext_vector_type(8)));
typedef float f32x4 __attribute__((ext_vector_type(4)));
typedef unsigned short us4 __attribute__((ext_vector_type(4)));
typedef unsigned short us8 __attribute__((ext_vector_type(8)));

static __device__ __forceinline__ unsigned short f2bf(float f) {
  unsigned u = __builtin_bit_cast(unsigned, f);
  u += 0x7fff + ((u >> 16) & 1);   // RNE
  return (unsigned short)(u >> 16);
}

static __device__ __forceinline__ unsigned short f2h(float f) {
  return __builtin_bit_cast(unsigned short, (_Float16)f);
}

static __device__ __forceinline__ float h2f(unsigned short u) {
  return (float)__builtin_bit_cast(_Float16, u);
}

static __device__ __forceinline__ short8 cvt8v(f32x4 a, f32x4 b) {
  short8 r;
  r[0] = (short)f2bf(a[0]); r[1] = (short)f2bf(a[1]);
  r[2] = (short)f2bf(a[2]); r[3] = (short)f2bf(a[3]);
  r[4] = (short)f2bf(b[0]); r[5] = (short)f2bf(b[1]);
  r[6] = (short)f2bf(b[2]); r[7] = (short)f2bf(b[3]);
  return r;
}

// Transpose + bf16-convert weights into workspace.
// WnS/WnR/WnE: [unit][k] plain.  Wt2: [unit][pk] with pk the GEMM2
// register-consumption permutation: pk = kk*32 + quad*8 + s, holding
// h-row keff = (s<4 ? 2*kk : 2*kk+1)*16 + quad*4 + (s&3). This lets one
// 16x16x32 MFMA consume two GEMM1 C-fragments directly from registers.
__global__ void prep_weights2(const float* __restrict__ W1,
                              const float* __restrict__ W2,
                              unsigned short* __restrict__ WnS,
                              unsigned short* __restrict__ WnR,
                              unsigned short* __restrict__ WnE,
                              unsigned short* __restrict__ Wt2) {
  int tid = blockIdx.x * 256 + threadIdx.x;   // 65536 total
  int seg = tid >> 14;
  int t = tid & 16383;
  int unit = t >> 7;
  int k = t & 127;
  if (seg == 0)      WnS[t] = f2bf(W1[k * 128 + unit]);
  else if (seg == 1) WnR[t] = f2bf(W1[(128 + k) * 128 + unit]);
  else if (seg == 2) WnE[t] = f2bf(W1[(256 + k) * 128 + unit]);
  else {
    int kk = k >> 5, rem = k & 31, q = rem >> 3, s = rem & 7;
    int keff = ((s < 4) ? (2 * kk) : (2 * kk + 1)) * 16 + q * 4 + (s & 3);
    Wt2[t] = f2bf(W2[keff * 128 + unit]);
  }
}

// Per-node projections Ps = node@W1s, Pr = node@W1r, stored fp16 in
// MFMA C-fragment order. 8 waves x 16 nodes per block; weights from LDS.
__global__ __launch_bounds__(512) void node_proj(
    const float* __restrict__ node,
    const unsigned short* __restrict__ WnS,
    const unsigned short* __restrict__ WnR,
    unsigned short* __restrict__ Ps,
    unsigned short* __restrict__ Pr) {
  __shared__ __align__(16) unsigned short wlds[2][16384];
  {
    const us8* s0 = (const us8*)WnS;
    const us8* s1 = (const us8*)WnR;
#pragma unroll
    for (int c = 0; c < 4; ++c) {
      int g = threadIdx.x + c * 512;
      int row = g >> 4, slot = g & 15;
      int dst = row * 128 + ((slot ^ (row & 7)) << 3);
      *(us8*)&wlds[0][dst] = s0[g];
      *(us8*)&wlds[1][dst] = s1[g];
    }
  }
  __syncthreads();

  const int lane = threadIdx.x & 63;
  const int wave = threadIdx.x >> 6;
  const int col = lane & 15;
  const int quad = lane >> 4;
  const int c7 = col & 7;
  const int nBase = blockIdx.x * 128 + wave * 16;
  if (nBase >= NNODES) return;   // NNODES % 16 == 0 -> wave-exact

  const float* src = node + (size_t)(nBase + col) * D + quad * 8;
  f32x4 c[4][2];
#pragma unroll
  for (int kk = 0; kk < 4; ++kk) {
    c[kk][0] = __builtin_nontemporal_load((const f32x4*)(src + kk * 32));
    c[kk][1] = __builtin_nontemporal_load((const f32x4*)(src + kk * 32 + 4));
  }
  f32x4 accS[8], accR[8];
  const f32x4 zero = {0.f, 0.f, 0.f, 0.f};
#pragma unroll
  for (int m = 0; m < 8; ++m) { accS[m] = zero; accR[m] = zero; }

#pragma unroll
  for (int kk = 0; kk < 4; ++kk) {
    short8 bf = cvt8v(c[kk][0], c[kk][1]);
#pragma unroll
    for (int m = 0; m < 8; ++m) {
      const int off = (m * 16 + col) * 128 + (((kk * 4 + quad) ^ c7) << 3);
      short8 as = *(const short8*)&wlds[0][off];
      accS[m] = __builtin_amdgcn_mfma_f32_16x16x32_bf16(as, bf, accS[m], 0, 0, 0);
      short8 ar = *(const short8*)&wlds[1][off];
      accR[m] = __builtin_amdgcn_mfma_f32_16x16x32_bf16(ar, bf, accR[m], 0, 0, 0);
    }
  }

  unsigned short* ps = Ps + (size_t)(nBase + col) * D + quad * 32;
  unsigned short* pr = Pr + (size_t)(nBase + col) * D + quad * 32;
#pragma unroll
  for (int m = 0; m < 8; m += 2) {
    us8 w1v, w2v;
#pragma unroll
    for (int r = 0; r < 4; ++r) {
      w1v[r] = f2h(accS[m][r]);     w1v[4 + r] = f2h(accS[m + 1][r]);
      w2v[r] = f2h(accR[m][r]);     w2v[4 + r] = f2h(accR[m + 1][r]);
    }
    *(us8*)(ps + m * 4) = w1v;
    *(us8*)(pr + m * 4) = w2v;
  }
}

// One wave = 16 edges. Weights from LDS; h never leaves registers
// (GEMM2 consumes GEMM1's C-fragments via the k-permuted Wt2 layout).
__global__ __launch_bounds__(512) void edge_mlp(
    const float* __restrict__ edge,
    const int* __restrict__ send, const int* __restrict__ recv,
    const unsigned short* __restrict__ WnE,
    const unsigned short* __restrict__ Wt2,
    const unsigned short* __restrict__ Ps,
    const unsigned short* __restrict__ Pr,
    const float* __restrict__ b1, const float* __restrict__ b2,
    const float* __restrict__ gamma, const float* __restrict__ beta,
    float* __restrict__ out) {
  __shared__ __align__(16) unsigned short wlds[2][16384];
  {
    const us8* s0 = (const us8*)WnE;
    const us8* s1 = (const us8*)Wt2;
#pragma unroll
    for (int c = 0; c < 4; ++c) {
      int g = threadIdx.x + c * 512;
      int row = g >> 4, slot = g & 15;
      int dst = row * 128 + ((slot ^ (row & 7)) << 3);
      *(us8*)&wlds[0][dst] = s0[g];
      *(us8*)&wlds[1][dst] = s1[g];
    }
  }
  __syncthreads();   // only barrier in the kernel

  const int lane = threadIdx.x & 63;
  const int wave = threadIdx.x >> 6;
  const int col = lane & 15;
  const int quad = lane >> 4;
  const int q4 = quad * 4;
  const int c7 = col & 7;
  const int eBase = blockIdx.x * 128 + wave * 16;
  if (eBase >= NEDGES) return;   // NEDGES % 16 == 0 -> wave-exact

  const int e = eBase + col;
  // indices first: their wait keeps the edge loads in flight
  const int si = send[e];
  const int ri = recv[e];

  const float* ge = edge + (size_t)e * D + quad * 8;
  f32x4 c[4][2];
#pragma unroll
  for (int kk = 0; kk < 4; ++kk) {
    c[kk][0] = __builtin_nontemporal_load((const f32x4*)(ge + kk * 32));
    c[kk][1] = __builtin_nontemporal_load((const f32x4*)(ge + kk * 32 + 4));
  }

  // gathers: 2 x 64B fp16 per lane, in flight across GEMM1
  const us8* ps = (const us8*)(Ps + (size_t)si * D + quad * 32);
  const us8* pr = (const us8*)(Pr + (size_t)ri * D + quad * 32);
  us8 gs[4], gr[4];
#pragma unroll
  for (int i = 0; i < 4; ++i) { gs[i] = ps[i]; gr[i] = pr[i]; }

  f32x4 acc[8];
#pragma unroll
  for (int m = 0; m < 8; ++m)
    acc[m] = *(const f32x4*)(b1 + m * 16 + q4);

  // GEMM1: h_e = edge @ W1e  (A-frags from swizzled LDS)
#pragma unroll
  for (int kk = 0; kk < 4; ++kk) {
    short8 bf = cvt8v(c[kk][0], c[kk][1]);
#pragma unroll
    for (int m = 0; m < 8; ++m) {
      const int off = (m * 16 + col) * 128 + (((kk * 4 + quad) ^ c7) << 3);
      short8 af = *(const short8*)&wlds[0][off];
      acc[m] = __builtin_amdgcn_mfma_f32_16x16x32_bf16(af, bf, acc[m], 0, 0, 0);
    }
  }

  // + Ps[send] + Pr[recv], ReLU, pack to bf16 B-frags (stay in registers)
  short8 hb[4];   // hb[i] packs C-frag blocks 2i (lo) and 2i+1 (hi)
#pragma unroll
  for (int m = 0; m < 8; ++m) {
    const int i = m >> 1, b = (m & 1) * 4;
    f32x4 v = acc[m];
#pragma unroll
    for (int r = 0; r < 4; ++r)
      v[r] += h2f(gs[i][b + r]) + h2f(gr[i][b + r]);
#pragma unroll
    for (int r = 0; r < 4; ++r)
      hb[i][b + r] = (short)f2bf(fmaxf(v[r], 0.f));
  }

  // GEMM2: out = h @ W2. hb[kk] holds h rows {2kk*16+quad*4+j} (j=0..3)
  // and {(2kk+1)*16+quad*4+j} (j=4..7) of column col -- Wt2's permuted
  // layout matches this k-assignment position-for-position.
  f32x4 acc2[8];
#pragma unroll
  for (int m = 0; m < 8; ++m)
    acc2[m] = *(const f32x4*)(b2 + m * 16 + q4);
#pragma unroll
  for (int kk = 0; kk < 4; ++kk) {
#pragma unroll
    for (int m = 0; m < 8; ++m) {
      const int off = (m * 16 + col) * 128 + (((kk * 4 + quad) ^ c7) << 3);
      short8 af = *(const short8*)&wlds[1][off];
      acc2[m] = __builtin_amdgcn_mfma_f32_16x16x32_bf16(af, hb[kk], acc2[m], 0, 0, 0);
    }
  }

  // LayerNorm + store
  float s = 0.f, ss = 0.f;
#pragma unroll
  for (int m = 0; m < 8; ++m)
#pragma unroll
    for (int r = 0; r < 4; ++r) {
      float v = acc2[m][r];
      s += v; ss += v * v;
    }
  s += __shfl_xor(s, 16);  s += __shfl_xor(s, 32);
  ss += __shfl_xor(ss, 16); ss += __shfl_xor(ss, 32);
  const float mean = s * (1.f / 128.f);
  const float var = ss * (1.f / 128.f) - mean * mean;
  const float rstd = rsqrtf(var + 1e-5f);
  float* op = out + (size_t)e * D;
#pragma unroll
  for (int m = 0; m < 8; ++m) {
    f32x4 gv = *(const f32x4*)(gamma + m * 16 + q4);
    f32x4 bv = *(const f32x4*)(beta + m * 16 + q4);
    f32x4 o;
#pragma unroll
    for (int r = 0; r < 4; ++r)
      o[r] = (acc2[m][r] - mean) * rstd * gv[r] + bv[r];
    __builtin_nontemporal_store(o, (f32x4*)(op + m * 16 + q4));
  }
}

// ---------------- fallback path (used only if ws too small) ----------------

__global__ void prep_weights(const float* __restrict__ W1,
                             const float* __restrict__ W2,
                             unsigned short* __restrict__ Wt1,
                             unsigned short* __restrict__ Wt2) {
  int tid = blockIdx.x * 256 + threadIdx.x;
  if (tid < 128 * 384) {
    int h = tid / 384, k = tid % 384;
    Wt1[tid] = f2bf(W1[k * 128 + h]);
  } else {
    int t2 = tid - 128 * 384;
    if (t2 < 128 * 128) {
      int o = t2 / 128, h = t2 % 128;
      Wt2[t2] = f2bf(W2[h * 128 + o]);
    }
  }
}

__global__ __launch_bounds__(256, 4) void edge_kernel(
    const float* __restrict__ node, const float* __restrict__ edge,
    const int* __restrict__ send, const int* __restrict__ recv,
    const unsigned short* __restrict__ Wt1,
    const unsigned short* __restrict__ Wt2,
    const float* __restrict__ b1, const float* __restrict__ b2,
    const float* __restrict__ gamma, const float* __restrict__ beta,
    float* __restrict__ out) {
  __shared__ unsigned short hbuf[4][32][136];

  const int lane = threadIdx.x & 63;
  const int wave = threadIdx.x >> 6;
  const int col = lane & 15;
  const int quad = lane >> 4;
  const int q4 = quad * 4;
  const int eBase = blockIdx.x * 128 + wave * 32;
  const bool active = eBase < NEDGES;

  if (active) {
    const int e0 = eBase + col;
    const int e1 = eBase + 16 + col;
    const float* g0s = node + (size_t)send[e0] * D;
    const float* g0r = node + (size_t)recv[e0] * D;
    const float* g0e = edge + (size_t)e0 * D;
    const float* g1s = node + (size_t)send[e1] * D;
    const float* g1r = node + (size_t)recv[e1] * D;
    const float* g1e = edge + (size_t)e1 * D;

    f32x4 acc[2][8];
#pragma unroll
    for (int m = 0; m < 8; ++m) {
      f32x4 bv = *(const f32x4*)(b1 + m * 16 + q4);
      acc[0][m] = bv; acc[1][m] = bv;
    }

    f32x4 pl[2][2][2];
#define SRC0(seg) ((seg) == 0 ? g0s : (seg) == 1 ? g0r : g0e)
#define SRC1(seg) ((seg) == 0 ? g1s : (seg) == 1 ? g1r : g1e)
#define ISSUE(kk, slot)                                         \
    {                                                           \
      const int seg_ = (kk) >> 2;                               \
      const int ks_ = ((kk) & 3) * 32 + quad * 8;               \
      pl[slot][0][0] = *(const f32x4*)(SRC0(seg_) + ks_);       \
      pl[slot][0][1] = *(const f32x4*)(SRC0(seg_) + ks_ + 4);   \
      pl[slot][1][0] = *(const f32x4*)(SRC1(seg_) + ks_);       \
      pl[slot][1][1] = *(const f32x4*)(SRC1(seg_) + ks_ + 4);   \
    }

    ISSUE(0, 0)
    ISSUE(1, 1)
#pragma unroll
    for (int kk = 0; kk < 12; ++kk) {
      const int slot = kk & 1;
      short8 bf0 = cvt8v(pl[slot][0][0], pl[slot][0][1]);
      short8 bf1 = cvt8v(pl[slot][1][0], pl[slot][1][1]);
      if (kk + 2 < 12) ISSUE(kk + 2, slot)
      const int kfull = kk * 32 + quad * 8;
#pragma unroll
      for (int m = 0; m < 8; ++m) {
        short8 af = *(const short8*)(Wt1 + (size_t)(m * 16 + col) * 384 + kfull);
        acc[0][m] = __builtin_amdgcn_mfma_f32_16x16x32_bf16(af, bf0, acc[0][m], 0, 0, 0);
        acc[1][m] = __builtin_amdgcn_mfma_f32_16x16x32_bf16(af, bf1, acc[1][m], 0, 0, 0);
      }
    }
#undef ISSUE
#undef SRC0
#undef SRC1

#pragma unroll
    for (int g = 0; g < 2; ++g) {
#pragma unroll
      for (int m = 0; m < 8; ++m) {
        f32x4 v = acc[g][m];
        us4 w;
        w.x = f2bf(v[0] > 0.f ? v[0] : 0.f);
        w.y = f2bf(v[1] > 0.f ? v[1] : 0.f);
        w.z = f2bf(v[2] > 0.f ? v[2] : 0.f);
        w.w = f2bf(v[3] > 0.f ? v[3] : 0.f);
        *(us4*)&hbuf[wave][g * 16 + col][m * 16 + q4] = w;
      }
    }
  }

  __syncthreads();

  if (active) {
    f32x4 acc2[2][8];
#pragma unroll
    for (int m = 0; m < 8; ++m) {
      f32x4 bv = *(const f32x4*)(b2 + m * 16 + q4);
      acc2[0][m] = bv; acc2[1][m] = bv;
    }
#pragma unroll
    for (int kk = 0; kk < 4; ++kk) {
      const int kb = kk * 32 + quad * 8;
      short8 bf0 = *(const short8*)&hbuf[wave][col][kb];
      short8 bf1 = *(const short8*)&hbuf[wave][16 + col][kb];
#pragma unroll
      for (int m = 0; m < 8; ++m) {
        short8 af = *(const short8*)(Wt2 + (size_t)(m * 16 + col) * 128 + kb);
        acc2[0][m] = __builtin_amdgcn_mfma_f32_16x16x32_bf16(af, bf0, acc2[0][m], 0, 0, 0);
        acc2[1][m] = __builtin_amdgcn_mfma_f32_16x16x32_bf16(af, bf1, acc2[1][m], 0, 0, 0);
      }
    }
#pragma unroll
    for (int g = 0; g < 2; ++g) {
      float s = 0.f, ss = 0.f;
#pragma unroll
      for (int m = 0; m < 8; ++m) {
#pragma unroll
        for (int r = 0; r < 4; ++r) {
          float v = acc2[g][m][r];
          s += v; ss += v * v;
        }
      }
      s += __shfl_xor(s, 16);  s += __shfl_xor(s, 32);
      ss += __shfl_xor(ss, 16); ss += __shfl_xor(ss, 32);
      const float mean = s * (1.f / 128.f);
      const float var = ss * (1.f / 128.f) - mean * mean;
      const float rstd = rsqrtf(var + 1e-5f);
      const int e = eBase + g * 16 + col;
      float* op = out + (size_t)e * D;
#pragma unroll
      for (int m = 0; m < 8; ++m) {
        f32x4 gv = *(const f32x4*)(gamma + m * 16 + q4);
        f32x4 bv = *(const f32x4*)(beta + m * 16 + q4);
        f32x4 o;
#pragma unroll
        for (int r = 0; r < 4; ++r)
          o[r] = (acc2[g][m][r] - mean) * rstd * gv[r] + bv[r];
        *(f32x4*)(op + m * 16 + q4) = o;
      }
    }
  }
}

extern "C" void kernel_launch(void* const* d_in, const int* in_sizes, int n_in,
                              void* d_out, int out_size, void* d_ws, size_t ws_size,
                              hipStream_t stream) {
  const float* node  = (const float*)d_in[0];
  const float* edge  = (const float*)d_in[1];
  const int*   send  = (const int*)d_in[2];
  const int*   recv  = (const int*)d_in[3];
  const float* W1    = (const float*)d_in[4];
  const float* b1    = (const float*)d_in[5];
  const float* W2    = (const float*)d_in[6];
  const float* b2    = (const float*)d_in[7];
  const float* gam   = (const float*)d_in[8];
  const float* bet   = (const float*)d_in[9];
  float* out = (float*)d_out;

  const size_t wbytes = (size_t)4 * 128 * 128 * sizeof(unsigned short);  // 128 KiB
  const size_t pbytes = (size_t)2 * NNODES * D * sizeof(unsigned short); // 51.2 MB

  if (ws_size >= wbytes + pbytes) {
    unsigned short* WnS = (unsigned short*)d_ws;
    unsigned short* WnR = WnS + 128 * 128;
    unsigned short* WnE = WnR + 128 * 128;
    unsigned short* Wt2 = WnE + 128 * 128;
    unsigned short* Ps  = Wt2 + 128 * 128;
    unsigned short* Pr  = Ps + (size_t)NNODES * D;

    prep_weights2<<<256, 256, 0, stream>>>(W1, W2, WnS, WnR, WnE, Wt2);
    node_proj<<<(NNODES + 127) / 128, 512, 0, stream>>>(node, WnS, WnR, Ps, Pr);
    edge_mlp<<<(NEDGES + 127) / 128, 512, 0, stream>>>(edge, send, recv, WnE, Wt2,
                                                       Ps, Pr, b1, b2, gam, bet, out);
  } else {
    unsigned short* Wt1 = (unsigned short*)d_ws;
    unsigned short* Wt2 = Wt1 + 128 * 384;
    prep_weights<<<256, 256, 0, stream>>>(W1, W2, Wt1, Wt2);
    const int nblocks = (NEDGES + 127) / 128;
    edge_kernel<<<nblocks, 256, 0, stream>>>(node, edge, send, recv, Wt1, Wt2,
                                             b1, b2, gam, bet, out);
  }
}